// Round 6
// baseline (327.072 us; speedup 1.0000x reference)
//
#include <hip/hip_runtime.h>

// GNN_base: per (b,l): c = ids[b,l]; neighbors n_k = ids[b, l+d], d in {-8..-1, 1..8} (0 outside).
// e_k = edge_w[n_k==0 ? 0 : c*VOCAB+n_k]; Mn[f] = max_k e_k * emb[n_k][f] (emb row 0 is zero,
// so n_k==0 terms contribute exactly 0). y[b,f] = sum_l (1-nw_c)*Mn[f] + nw_c*emb[c][f].
//
// R6 structure: single-round grid (1024 blocks = 4/CU exactly). Each block handles 2 chunks
// of 16 positions (48-token window). BOTH chunks' random edge gathers issue upfront (chunk-1
// latency hidden behind chunk-0 staging+compute; s_ew double-buffered). The 32-row emb LDS
// window is reused across chunks; chunk-1 stage loads issue before the barrier to overlap
// the compute tail. Wave owns 4 consecutive positions; 20-row union window read once each
// (ds_read_b128), applied via compile-time (j,q) conditions. No atomics: per-block partial
// rows to ws, tiny reduce kernel sums 64 partials.

#define VOCAB  8000
#define FDIM   256
#define PNB    8
#define NK     16
#define BB     16
#define LL     2048
#define CHUNK  16               // positions per chunk
#define CPB    2                // chunks per block
#define SPAN   (CHUNK * CPB)    // 32 positions per block
#define WIN    (CHUNK + 2*PNB)  // 32 emb rows per chunk window
#define TOKW   (SPAN + 2*PNB)   // 48 tokens per block
#define NBLK   (LL / SPAN)      // 64 blocks per batch row

__global__ __launch_bounds__(256) void gnn_kernel(
    const int*   __restrict__ ids,      // B*L
    const float* __restrict__ emb,      // VOCAB*FDIM (row 0 == 0)
    const float* __restrict__ edge_w,   // VOCAB*VOCAB+1
    const float* __restrict__ node_w,   // VOCAB
    float*       __restrict__ ws)       // partials: [BB][NBLK][FDIM]
{
    __shared__ float s_emb[WIN][FDIM];      // 32 KB window (reused per chunk)
    __shared__ float s_ew [CPB][CHUNK][NK]; // 2 KB edge weights, both chunks
    __shared__ int   s_tok[TOKW];
    __shared__ float s_nw [SPAN];
    __shared__ float s_red[4][FDIM];        // 4 KB cross-wave reduce

    const int b   = blockIdx.y;
    const int bx  = blockIdx.x;
    const int l0  = bx * SPAN;
    const int tid = threadIdx.x;
    const int* idrow = ids + b * LL;

    // ---- Phase A: token window (positions l0-8 .. l0+SPAN+7) ----
    if (tid < TOKW) {
        const int p = l0 - PNB + tid;
        int t = (p >= 0 && p < LL) ? idrow[p] : 0;
        t = (t < 0) ? 0 : ((t >= VOCAB) ? (VOCAB - 1) : t);   // safety clamp
        s_tok[tid] = t;
    }
    __syncthreads();

    // ---- Phase B: ALL edge gathers (both chunks) issued upfront (long latency,
    // random in 256 MB -> HBM; nontemporal: zero reuse, don't evict emb).
    const int ll = tid >> 4;          // 0..15
    const int k  = tid & (NK - 1);
    const int ko = k + (k >= PNB ? 1 : 0);
    const int n0 = s_tok[ll + ko];
    const int c0 = s_tok[ll + PNB];
    const int n1 = s_tok[CHUNK + ll + ko];
    const int c1 = s_tok[CHUNK + ll + PNB];
    const float e0 = __builtin_nontemporal_load(
        edge_w + ((n0 == 0) ? 0LL : (long long)c0 * VOCAB + n0));
    const float e1 = __builtin_nontemporal_load(
        edge_w + ((n1 == 0) ? 0LL : (long long)c1 * VOCAB + n1));

    // ---- Phase B0: chunk-0 emb window loads (rows = s_tok[0..32)) ----
    float4 rr[8];
    #pragma unroll
    for (int j = 0; j < 8; ++j) {
        const int i    = tid + 256 * j;
        const int row  = i >> 6;
        const int col4 = (i & 63) << 2;
        rr[j] = *(const float4*)(emb + (size_t)s_tok[row] * FDIM + col4);
    }
    s_ew[0][ll][k] = e0;
    s_ew[1][ll][k] = e1;
    if (tid < SPAN) s_nw[tid] = node_w[s_tok[tid + PNB]];
    #pragma unroll
    for (int j = 0; j < 8; ++j) {
        const int i    = tid + 256 * j;
        const int row  = i >> 6;
        const int col4 = (i & 63) << 2;
        *(float4*)&s_emb[row][col4] = rr[j];
    }
    __syncthreads();

    // ---- Phase C: compute both chunks; wave owns 4 consecutive positions ----
    const int wave = tid >> 6;
    const int lane = tid & 63;
    const int f0   = lane << 2;
    const int base = wave << 2;

    float4 acc = make_float4(0.f, 0.f, 0.f, 0.f);

    #pragma unroll 1
    for (int ch = 0; ch < CPB; ++ch) {
        float4 m[4], rc[4];
        #pragma unroll
        for (int q = 0; q < 4; ++q)
            m[q] = make_float4(-INFINITY, -INFINITY, -INFINITY, -INFINITY);

        #pragma unroll
        for (int j = 0; j < 20; ++j) {
            const float4 r = *(const float4*)&s_emb[base + j][f0];  // ds_read_b128, once
            #pragma unroll
            for (int q = 0; q < 4; ++q) {
                const int d = j - q;                  // compile-time per (j,q)
                if (d < 0 || d > 16) continue;
                if (d == 8) { rc[q] = r; continue; }  // center row
                const int   kk = (d < 8) ? d : d - 1;
                const float e  = s_ew[ch][base + q][kk];   // LDS broadcast
                m[q].x = fmaxf(m[q].x, e * r.x);
                m[q].y = fmaxf(m[q].y, e * r.y);
                m[q].z = fmaxf(m[q].z, e * r.z);
                m[q].w = fmaxf(m[q].w, e * r.w);
            }
        }
        #pragma unroll
        for (int q = 0; q < 4; ++q) {
            const float nw = s_nw[ch * CHUNK + base + q];
            const float w1 = 1.0f - nw;
            acc.x += w1 * m[q].x + nw * rc[q].x;
            acc.y += w1 * m[q].y + nw * rc[q].y;
            acc.z += w1 * m[q].z + nw * rc[q].z;
            acc.w += w1 * m[q].w + nw * rc[q].w;
        }

        if (ch == 0) {
            // Issue chunk-1 window loads BEFORE the barrier (overlap compute tail),
            // write after it (buffer reuse). Rows = s_tok[16..48).
            float4 r2[8];
            #pragma unroll
            for (int j = 0; j < 8; ++j) {
                const int i    = tid + 256 * j;
                const int row  = i >> 6;
                const int col4 = (i & 63) << 2;
                r2[j] = *(const float4*)(emb + (size_t)s_tok[CHUNK + row] * FDIM + col4);
            }
            __syncthreads();   // everyone done reading chunk-0 window
            #pragma unroll
            for (int j = 0; j < 8; ++j) {
                const int i    = tid + 256 * j;
                const int row  = i >> 6;
                const int col4 = (i & 63) << 2;
                *(float4*)&s_emb[row][col4] = r2[j];
            }
            __syncthreads();
        }
    }

    // ---- Phase D: cross-wave reduce, coalesced partial-row store ----
    ((float4*)s_red[wave])[lane] = acc;
    __syncthreads();

    const float s = s_red[0][tid] + s_red[1][tid] + s_red[2][tid] + s_red[3][tid];
    ws[((size_t)b * NBLK + bx) * FDIM + tid] = s;
}

__global__ __launch_bounds__(256) void gnn_reduce(
    const float* __restrict__ ws,   // [BB][NBLK][FDIM] partials
    float*       __restrict__ out)  // [BB][FDIM]
{
    const int b = blockIdx.x;
    const int f = threadIdx.x;
    const float* p = ws + (size_t)b * NBLK * FDIM + f;
    float s = 0.0f;
    #pragma unroll 8
    for (int c = 0; c < NBLK; ++c)
        s += p[(size_t)c * FDIM];
    out[b * FDIM + f] = s;
}

extern "C" void kernel_launch(void* const* d_in, const int* in_sizes, int n_in,
                              void* d_out, int out_size, void* d_ws, size_t ws_size,
                              hipStream_t stream) {
    // Select inputs by element count (all four distinct) — immune to ordering.
    const int*   ids    = nullptr;
    const float* emb    = nullptr;
    const float* edge_w = nullptr;
    const float* node_w = nullptr;
    for (int i = 0; i < n_in; ++i) {
        const long long sz = in_sizes[i];
        if      (sz == (long long)BB * LL)            ids    = (const int*)  d_in[i];
        else if (sz == (long long)VOCAB * FDIM)       emb    = (const float*)d_in[i];
        else if (sz == (long long)VOCAB * VOCAB + 1)  edge_w = (const float*)d_in[i];
        else if (sz == (long long)VOCAB)              node_w = (const float*)d_in[i];
    }
    float* out = (float*)d_out;
    float* ws  = (float*)d_ws;   // 1 MB of scratch; fully written before read

    dim3 grid(NBLK, BB);         // 1024 blocks = 4 per CU, single round
    gnn_kernel<<<grid, 256, 0, stream>>>(ids, emb, edge_w, node_w, ws);
    gnn_reduce<<<dim3(BB), 256, 0, stream>>>(ws, out);
}

// Round 7
// 318.830 us; speedup vs baseline: 1.0259x; 1.0259x over previous
//
#include <hip/hip_runtime.h>

// GNN_base: per (b,l): c = ids[b,l]; neighbors n_k = ids[b, l+d], d in {-8..-1, 1..8} (0 outside).
// e_k = edge_w[n_k==0 ? 0 : c*VOCAB+n_k]; Mn[f] = max_k e_k * emb[n_k][f] (emb row 0 is zero,
// so n_k==0 terms contribute exactly 0). y[b,f] = sum_l (1-nw_c)*Mn[f] + nw_c*emb[c][f].
//
// R7 = revert to R5 (best measured: 317.5 us, absmax 0.0). Structure: a chunk of CHUNK
// positions touches only CHUNK+16 distinct emb rows -> stage the window in LDS once. Each
// wave owns 4 consecutive positions; union window = 20 rows, each read once (ds_read_b128),
// applied via compile-time (j,q) conditions. Epilogue: NO atomics — per-block partial rows
// to d_ws, tiny second kernel reduces 128 partials per output element (L2-resident).
// R6's 2-chunk pipelined variant regressed (+9.6 us: register pressure + lost block-level
// oversubscription); do not re-attempt.

#define VOCAB 8000
#define FDIM  256
#define PNB   8
#define NK    16
#define BB    16
#define LL    2048
#define CHUNK 16              // l-positions per block
#define WIN   (CHUNK + 2*PNB) // 32 distinct emb rows per block
#define NCHUNK (LL / CHUNK)   // 128 blocks per batch row

__global__ __launch_bounds__(256) void gnn_kernel(
    const int*   __restrict__ ids,      // B*L
    const float* __restrict__ emb,      // VOCAB*FDIM (row 0 == 0)
    const float* __restrict__ edge_w,   // VOCAB*VOCAB+1
    const float* __restrict__ node_w,   // VOCAB
    float*       __restrict__ ws)       // partials: [BB][NCHUNK][FDIM]
{
    __shared__ float s_emb[WIN][FDIM];   // 32 KB staged embedding window
    __shared__ float s_ew [CHUNK][NK];   // 1 KB edge weights
    __shared__ int   s_tok[WIN];
    __shared__ float s_nw [CHUNK];
    __shared__ float s_red[4][FDIM];     // 4 KB cross-wave reduce

    const int b   = blockIdx.y;
    const int l0  = blockIdx.x * CHUNK;
    const int tid = threadIdx.x;
    const int* idrow = ids + b * LL;

    // ---- Phase A: window token ids (positions l0-8 .. l0+CHUNK+7) ----
    if (tid < WIN) {
        const int p = l0 - PNB + tid;
        int t = (p >= 0 && p < LL) ? idrow[p] : 0;
        t = (t < 0) ? 0 : ((t >= VOCAB) ? (VOCAB - 1) : t);   // safety clamp
        s_tok[tid] = t;
    }
    __syncthreads();

    // ---- Phase B: random edge-weight gathers (issue first: long latency).
    // Nontemporal: zero reuse — don't evict emb from L2/L3.
    {   // CHUNK*NK = 256 gathers, exactly one per thread
        const int ll = tid >> 4;
        const int k  = tid & (NK - 1);
        const int n  = s_tok[ll + k + (k >= PNB ? 1 : 0)];
        const int c  = s_tok[ll + PNB];
        const long long ei = (n == 0) ? 0LL : (long long)c * VOCAB + n;
        s_ew[ll][k] = __builtin_nontemporal_load(edge_w + ei);
        if (tid < CHUNK) s_nw[tid] = node_w[s_tok[tid + PNB]];
    }
    // ---- Phase B': stage WIN emb rows into LDS (coalesced float4) ----
    {   // WIN rows * 64 float4/row = 2048 float4 over 256 threads = 8 each
        #pragma unroll
        for (int j = 0; j < 8; ++j) {
            const int i    = tid + 256 * j;
            const int row  = i >> 6;
            const int col4 = (i & 63) << 2;
            const float4 v = *(const float4*)(emb + (size_t)s_tok[row] * FDIM + col4);
            *(float4*)&s_emb[row][col4] = v;
        }
    }
    __syncthreads();

    // ---- Phase C: wave w owns positions 4w..4w+3; union window = rows 4w..4w+19.
    const int wave = tid >> 6;
    const int lane = tid & 63;
    const int f0   = lane << 2;
    const int base = wave << 2;

    float4 m[4], rc[4];
    #pragma unroll
    for (int q = 0; q < 4; ++q)
        m[q] = make_float4(-INFINITY, -INFINITY, -INFINITY, -INFINITY);

    #pragma unroll
    for (int j = 0; j < 20; ++j) {
        const float4 r = *(const float4*)&s_emb[base + j][f0];  // ds_read_b128, once
        #pragma unroll
        for (int q = 0; q < 4; ++q) {
            const int d = j - q;                  // compile-time per (j,q)
            if (d < 0 || d > 16) continue;        // outside this position's window
            if (d == 8) { rc[q] = r; continue; }  // center row: capture for blend
            const int   k = (d < 8) ? d : d - 1;  // neighbor slot
            const float e = s_ew[base + q][k];    // LDS broadcast — conflict-free
            m[q].x = fmaxf(m[q].x, e * r.x);
            m[q].y = fmaxf(m[q].y, e * r.y);
            m[q].z = fmaxf(m[q].z, e * r.z);
            m[q].w = fmaxf(m[q].w, e * r.w);
        }
    }

    float4 acc = make_float4(0.f, 0.f, 0.f, 0.f);
    #pragma unroll
    for (int q = 0; q < 4; ++q) {
        const float nw = s_nw[base + q];
        const float w1 = 1.0f - nw;
        acc.x += w1 * m[q].x + nw * rc[q].x;
        acc.y += w1 * m[q].y + nw * rc[q].y;
        acc.z += w1 * m[q].z + nw * rc[q].z;
        acc.w += w1 * m[q].w + nw * rc[q].w;
    }

    // ---- Phase D: cross-wave reduce in LDS, coalesced partial-row store (NO atomics) ----
    ((float4*)s_red[wave])[lane] = acc;
    __syncthreads();

    const float s = s_red[0][tid] + s_red[1][tid] + s_red[2][tid] + s_red[3][tid];
    ws[((size_t)b * NCHUNK + blockIdx.x) * FDIM + tid] = s;
}

__global__ __launch_bounds__(256) void gnn_reduce(
    const float* __restrict__ ws,   // [BB][NCHUNK][FDIM] partials
    float*       __restrict__ out)  // [BB][FDIM]
{
    const int b = blockIdx.x;
    const int f = threadIdx.x;
    const float* p = ws + (size_t)b * NCHUNK * FDIM + f;
    float s = 0.0f;
    #pragma unroll 8
    for (int c = 0; c < NCHUNK; ++c)
        s += p[(size_t)c * FDIM];
    out[b * FDIM + f] = s;
}

extern "C" void kernel_launch(void* const* d_in, const int* in_sizes, int n_in,
                              void* d_out, int out_size, void* d_ws, size_t ws_size,
                              hipStream_t stream) {
    // Select inputs by element count (all four distinct) — immune to ordering.
    const int*   ids    = nullptr;
    const float* emb    = nullptr;
    const float* edge_w = nullptr;
    const float* node_w = nullptr;
    for (int i = 0; i < n_in; ++i) {
        const long long sz = in_sizes[i];
        if      (sz == (long long)BB * LL)            ids    = (const int*)  d_in[i];
        else if (sz == (long long)VOCAB * FDIM)       emb    = (const float*)d_in[i];
        else if (sz == (long long)VOCAB * VOCAB + 1)  edge_w = (const float*)d_in[i];
        else if (sz == (long long)VOCAB)              node_w = (const float*)d_in[i];
    }
    float* out = (float*)d_out;
    float* ws  = (float*)d_ws;   // 2 MB of the scratch; fully written before read

    dim3 grid(NCHUNK, BB);
    gnn_kernel<<<grid, 256, 0, stream>>>(ids, emb, edge_w, node_w, ws);
    gnn_reduce<<<dim3(BB), 256, 0, stream>>>(ws, out);
}